// Round 4
// baseline (1142.983 us; speedup 1.0000x reference)
//
#include <hip/hip_runtime.h>
#include <hip/hip_bf16.h>
#include <stdint.h>

// Problem constants
#define B_    256
#define T_    128
#define W_    32
#define H_    512
#define G4_   2048   // 4*H
#define TW_   96     // warm steps
#define STEPS_ 191   // 96 warm + 95 decode cells
#define TEAMS 8
#define MEMBERS 16
#define ROWS  32     // batch rows per team
#define HC    32     // h-columns per block (over all gates: 32 of 512)

typedef __attribute__((ext_vector_type(8))) short short8;
typedef __attribute__((ext_vector_type(4))) float f32x4;

__device__ __forceinline__ unsigned short f2bf(float f) {
  uint32_t u = __float_as_uint(f);
  u += 0x7fffu + ((u >> 16) & 1u);   // round-to-nearest-even
  return (unsigned short)(u >> 16);
}
__device__ __forceinline__ float sigm(float x) { return 1.f / (1.f + __expf(-x)); }
__device__ __forceinline__ float tanh_(float x) { return 1.f - 2.f / (1.f + __expf(2.f * x)); }

// Coherent (device-scope) accesses without cache-maintenance instructions:
// relaxed agent atomics -> global_load/store ... sc0 sc1 (no buffer_wbl2/inv).
#define LOAD_C64(p)     __hip_atomic_load((p), __ATOMIC_RELAXED, __HIP_MEMORY_SCOPE_AGENT)
#define LOAD_CF(p)      __hip_atomic_load((p), __ATOMIC_RELAXED, __HIP_MEMORY_SCOPE_AGENT)
#define STORE_C64(p,v)  __hip_atomic_store((p), (v), __ATOMIC_RELAXED, __HIP_MEMORY_SCOPE_AGENT)
#define STORE_C32(p,v)  __hip_atomic_store((p), (v), __ATOMIC_RELAXED, __HIP_MEMORY_SCOPE_AGENT)
#define STORE_CF(p,v)   __hip_atomic_store((p), (v), __ATOMIC_RELAXED, __HIP_MEMORY_SCOPE_AGENT)

// ---------------------------------------------------------------------------
// Persistent LSTM. 128 blocks x 256 threads. team=blockIdx&7 (rows team*32..),
// member=blockIdx>>3 (h-cols member*32..). Each wave owns 8 h-cols x 4 gates.
// Transposed MFMA: A = Wr^T fragments (VGPR-resident), B = h^T from LDS.
// Output lane layout: col(l16)=batch-row, row(l4*4+j) = hc(l4)*4 + gate(j)
// => all 4 gates of one cell in one lane => in-register cell update.
// Decoder pred exchanged as per-block partial sums (pp) alongside h.
// pp buffers are [256 global rows][16 members][2] — partitioned per team.
// ---------------------------------------------------------------------------
__global__ __launch_bounds__(256, 1) void lstm_kernel(
    const float* __restrict__ inputs, const float* __restrict__ Wk,
    const float* __restrict__ Wr, const float* __restrict__ bias,
    const float* __restrict__ Ww, const float* __restrict__ bw,
    unsigned short* __restrict__ h0buf, unsigned short* __restrict__ h1buf,
    float* __restrict__ pp0, float* __restrict__ pp1,
    unsigned short* __restrict__ warm, int* __restrict__ flags,
    float* __restrict__ out_pred)
{
  const int team = blockIdx.x & 7;
  const int member = blockIdx.x >> 3;   // 0..15
  const int rbase = team * ROWS;
  const int hbase = member * HC;
  const int tid = threadIdx.x;
  const int wave = tid >> 6;
  const int lane = tid & 63;
  const int l4 = lane >> 4, l16 = lane & 15;

  __shared__ unsigned short h_lds[ROWS][H_];     // 32KB, granule-XOR swizzled
  __shared__ float x_all_lds[TW_][ROWS][2];      // 24KB warm inputs
  __shared__ float x_lds[ROWS][2];               // decode x (pred)
  __shared__ float pp_lds[4][ROWS][2];           // per-wave pred partials

  for (int i = tid; i < TW_*ROWS*2; i += 256) {
    int tt = i >> 6, row = (i >> 1) & 31, c = i & 1;
    x_all_lds[tt][row][c] = inputs[(size_t)(rbase+row)*(T_*2) + (W_+tt)*2 + c];
  }

  // ---- persistent per-lane constants ----
  const int gateL = l16 & 3, hclL = l16 >> 2;
  short8 afrag[2][16];          // Wr^T fragments: 128 VGPRs
  float bbv[2][4], wk0v[2][4], wk1v[2][4], wwv[2][2];
#pragma unroll
  for (int a = 0; a < 2; a++) {
    const int gcA = gateL*H_ + hbase + wave*8 + a*4 + hclL;   // A-row source col
#pragma unroll
    for (int ks = 0; ks < 16; ks++) {
      const float* wp = Wr + (size_t)(ks*32 + l4*8) * G4_ + gcA;
#pragma unroll
      for (int j = 0; j < 8; j++) afrag[a][ks][j] = (short)f2bf(wp[(size_t)j * G4_]);
    }
    const int colA = hbase + wave*8 + a*4 + l4;               // this lane's h-col
#pragma unroll
    for (int j = 0; j < 4; j++) {
      int gcj = j*H_ + colA;                                   // gate j, col colA
      bbv[a][j] = bias[gcj]; wk0v[a][j] = Wk[gcj]; wk1v[a][j] = Wk[G4_ + gcj];
    }
    wwv[a][0] = Ww[2*colA]; wwv[a][1] = Ww[2*colA + 1];
  }
  const float bwc0 = bw[0], bwc1 = bw[1];
  float creg[2][2] = {{0.f,0.f},{0.f,0.f}};
  __syncthreads();

  int* tflags = flags + team * MEMBERS;
  const int srow = tid >> 3, sg = tid & 7;      // h-stage decomposition

  for (int t = 0; t < STEPS_; t++) {
    const unsigned short* hprev = (t & 1) ? h1buf : h0buf;
    unsigned short* hnext = (t & 1) ? h0buf : h1buf;
    const float* ppprev = (t & 1) ? pp1 : pp0;
    float* ppnext = (t & 1) ? pp0 : pp1;

    // ---- stage: decode-x (pp sum) + h slice -> LDS ----
    if (t >= TW_ && tid < 64) {
      int row = tid >> 1, c = tid & 1;
      const float* pps = ppprev + (size_t)(rbase+row)*32 + c;  // [grow][16][2]
      float s = c ? bwc1 : bwc0;
#pragma unroll
      for (int m = 0; m < 16; m++) s += LOAD_CF(pps + m*2);
      x_lds[row][c] = s;
      if (member == 0)
        out_pred[((size_t)(rbase+row)*96 + (t - TW_))*2 + c] = s;
    }
    {
      const uint64_t* src = (const uint64_t*)(hprev + (size_t)(rbase+srow)*H_ + sg*8);
      uint64_t q[16];
#pragma unroll
      for (int i = 0; i < 8; i++) {
        q[2*i]   = LOAD_C64(src + (size_t)i*16);
        q[2*i+1] = LOAD_C64(src + (size_t)i*16 + 1);
      }
#pragma unroll
      for (int i = 0; i < 8; i++) {
        int gr = sg + 8*i;
        uint64_t* d = (uint64_t*)&h_lds[srow][(gr ^ (srow & 7)) * 8];
        d[0] = q[2*i]; d[1] = q[2*i+1];
      }
    }
    __syncthreads();   // S1

    // ---- z^T = Wr^T @ h^T (+ bias + Wk*x), MFMA over K=512 ----
    f32x4 acc[2][2];
    const float* xsrc = (t < TW_) ? &x_all_lds[t][0][0] : &x_lds[0][0];
#pragma unroll
    for (int a = 0; a < 2; a++)
#pragma unroll
      for (int n = 0; n < 2; n++) {
        int r = n*16 + l16;
        float x0 = xsrc[r*2], x1 = xsrc[r*2+1];
#pragma unroll
        for (int j = 0; j < 4; j++)
          acc[a][n][j] = bbv[a][j] + wk0v[a][j]*x0 + wk1v[a][j]*x1;
      }
#pragma unroll
    for (int ks = 0; ks < 16; ks++) {
      int pg = ((ks*4 + l4) ^ (l16 & 7)) * 8;    // swizzled granule
      short8 b0 = *(const short8*)&h_lds[l16][pg];
      short8 b1 = *(const short8*)&h_lds[16 + l16][pg];
      acc[0][0] = __builtin_amdgcn_mfma_f32_16x16x32_bf16(afrag[0][ks], b0, acc[0][0], 0,0,0);
      acc[0][1] = __builtin_amdgcn_mfma_f32_16x16x32_bf16(afrag[0][ks], b1, acc[0][1], 0,0,0);
      acc[1][0] = __builtin_amdgcn_mfma_f32_16x16x32_bf16(afrag[1][ks], b0, acc[1][0], 0,0,0);
      acc[1][1] = __builtin_amdgcn_mfma_f32_16x16x32_bf16(afrag[1][ks], b1, acc[1][1], 0,0,0);
    }

    // ---- in-register cell update + packed h store + pred partials ----
    float pp0v[2] = {0.f, 0.f}, pp1v[2] = {0.f, 0.f};
#pragma unroll
    for (int a = 0; a < 2; a++)
#pragma unroll
      for (int n = 0; n < 2; n++) {
        float zi = acc[a][n][0], zf = acc[a][n][1];
        float zg = acc[a][n][2], zo = acc[a][n][3];
        float cn = sigm(zf)*creg[a][n] + sigm(zi)*tanh_(zg);
        float hn = sigm(zo)*tanh_(cn);
        creg[a][n] = cn;
        pp0v[n] += hn * wwv[a][0];
        pp1v[n] += hn * wwv[a][1];
        // pack 4 l4-lanes (adjacent cols) into one 8B store from l4==0
        int v = (int)f2bf(hn);
        int v1 = __shfl_xor(v, 16);
        uint32_t lo = (uint32_t)(v & 0xffff) | ((uint32_t)(v1 & 0xffff) << 16);
        int r2 = __shfl_xor((int)lo, 32);
        uint64_t u = (uint64_t)lo | ((uint64_t)(uint32_t)r2 << 32);
        if (l4 == 0) {
          int row = rbase + n*16 + l16;
          int col0 = hbase + wave*8 + a*4;
          STORE_C64((uint64_t*)(hnext + (size_t)row*H_ + col0), u);
          if (t == TW_ - 1)
            *(uint64_t*)(warm + (size_t)row*H_ + col0) = u;
        }
      }
    if (t >= TW_ - 1) {
#pragma unroll
      for (int n = 0; n < 2; n++) {
        pp0v[n] += __shfl_xor(pp0v[n], 16); pp0v[n] += __shfl_xor(pp0v[n], 32);
        pp1v[n] += __shfl_xor(pp1v[n], 16); pp1v[n] += __shfl_xor(pp1v[n], 32);
        if (l4 == 0) {
          pp_lds[wave][n*16 + l16][0] = pp0v[n];
          pp_lds[wave][n*16 + l16][1] = pp1v[n];
        }
      }
    }
    __syncthreads();   // S2 (pp_lds ready; MFMA h_lds reads done)

    if (t >= TW_ - 1 && tid < 64) {
      int row = tid >> 1, c = tid & 1;
      float s = pp_lds[0][row][c] + pp_lds[1][row][c]
              + pp_lds[2][row][c] + pp_lds[3][row][c];
      STORE_CF(ppnext + (size_t)(rbase+row)*32 + member*2 + c, s);
    }

    // ---- team barrier: drain all stores, flag, hard poll ----
    asm volatile("s_waitcnt vmcnt(0)" ::: "memory");
    __syncthreads();   // S3: every wave drained
    if (tid == 0)
      STORE_C32(&tflags[member], t + 1);
    if (tid < 8) {
      const uint64_t* fp = (const uint64_t*)tflags + tid;   // 2 flags/thread
      uint32_t need = (uint32_t)(t + 1);
      for (;;) {
        uint64_t v = LOAD_C64(fp);
        if ((uint32_t)v >= need && (uint32_t)(v >> 32) >= need) break;
      }
    }
    __syncthreads();   // S4
  }

  // ---- final pred (k=95) from pp of step 190 (pp1 side) ----
  if (member == 0 && tid < 64) {
    int row = tid >> 1, c = tid & 1;
    const float* pps = pp1 + (size_t)(rbase+row)*32 + c;
    float s = c ? bwc1 : bwc0;
#pragma unroll
    for (int m = 0; m < 16; m++) s += LOAD_CF(pps + m*2);
    out_pred[((size_t)(rbase+row)*96 + 95)*2 + c] = s;
  }
}

// ---------------------------------------------------------------------------
// cat = [warm_out (bf16) | relu(inputs[:, :31] @ Wc + bc)] as bf16 [256][16384]
// ---------------------------------------------------------------------------
__global__ void build_cat_kernel(
    const float* __restrict__ inputs, const float* __restrict__ Wc,
    const float* __restrict__ bc, const unsigned short* __restrict__ warm,
    unsigned short* __restrict__ cat)
{
  int idx = (blockIdx.x * 256 + threadIdx.x) * 4;   // 4096 blocks
  int b = idx >> 14, k0 = idx & 16383;
  uint2 out;
  if (k0 < 512) {
    out = *(const uint2*)(warm + (size_t)b*512 + k0);
  } else {
    int kk = k0 - 512;
    int w = kk >> 9;
    int hc = kk & 511;
    float x0 = inputs[(size_t)b*256 + w*2], x1 = inputs[(size_t)b*256 + w*2 + 1];
    unsigned short v[4];
#pragma unroll
    for (int j = 0; j < 4; j++) {
      float val = x0 * Wc[hc+j] + x1 * Wc[512 + hc + j] + bc[hc+j];
      v[j] = f2bf(fmaxf(val, 0.f));
    }
    out.x = (uint32_t)v[0] | ((uint32_t)v[1] << 16);
    out.y = (uint32_t)v[2] | ((uint32_t)v[3] << 16);
  }
  *(uint2*)(cat + idx) = out;
}

// ---------------------------------------------------------------------------
// Transposed GEMM: partialT[kc][n][b] = sum_k Wcc[k][n]*cat[b][k] over k-chunk.
// ---------------------------------------------------------------------------
__global__ __launch_bounds__(256, 1) void gemm_kernel(
    const unsigned short* __restrict__ cat, const float* __restrict__ Wcc,
    float* __restrict__ partialT)
{
  const int nc = blockIdx.x & 15;
  const int kc = blockIdx.x >> 4;
  const int tid = threadIdx.x;
  const int w = tid >> 6, lane = tid & 63;
  const int l4 = lane >> 4, l16 = lane & 15;

  f32x4 zero = {0.f, 0.f, 0.f, 0.f};
  f32x4 acc[16];
#pragma unroll
  for (int i = 0; i < 16; i++) acc[i] = zero;

  const int kbase = kc * 2048;
  const int nrow = nc*64 + w*16 + l16;

  for (int ks = 0; ks < 64; ks++) {
    const float* wp = Wcc + (size_t)(kbase + ks*32 + l4*8) * 1024 + nrow;
    short8 af;
#pragma unroll
    for (int j = 0; j < 8; j++) af[j] = (short)f2bf(wp[(size_t)j * 1024]);
    const unsigned short* cp = cat + kbase + ks*32 + l4*8;
#pragma unroll
    for (int bt = 0; bt < 16; bt++) {
      short8 bf = *(const short8*)(cp + (size_t)(bt*16 + l16) * 16384);
      acc[bt] = __builtin_amdgcn_mfma_f32_16x16x32_bf16(af, bf, acc[bt], 0, 0, 0);
    }
  }

  float* pp = partialT + (size_t)kc*1024*256 + (size_t)(nc*64 + w*16 + l4*4)*256 + l16;
#pragma unroll
  for (int bt = 0; bt < 16; bt++) {
#pragma unroll
    for (int r = 0; r < 4; r++)
      pp[(size_t)r*256 + bt*16] = acc[bt][r];
  }
}

// ctT[n][b] = relu(bcc[n] + sum_p partialT[p][n][b])
__global__ void reduce_kernel(const float* __restrict__ partialT,
                              const float* __restrict__ bcc, float* __restrict__ ctT)
{
  int e = blockIdx.x * 256 + threadIdx.x;   // 1024 blocks
  int n = e >> 8;
  float s = bcc[n];
#pragma unroll
  for (int p = 0; p < 8; p++) s += partialT[(size_t)p*262144 + e];
  ctT[e] = fmaxf(s, 0.f);
}

// cost/prob heads: one wave per batch row
__global__ void head_kernel(const float* __restrict__ ctT, const float* __restrict__ Wp,
                            const float* __restrict__ bp, const float* __restrict__ Wco,
                            const float* __restrict__ bco, float* __restrict__ out)
{
  int b = blockIdx.x;
  int lane = threadIdx.x;
  float p0 = 0.f, p1 = 0.f, pc = 0.f;
#pragma unroll
  for (int i = 0; i < 16; i++) {
    int n = i*64 + lane;
    float c = ctT[(size_t)n*256 + b];
    p0 += c * Wp[2*n]; p1 += c * Wp[2*n+1]; pc += c * Wco[n];
  }
  for (int m = 1; m < 64; m <<= 1) {
    p0 += __shfl_xor(p0, m); p1 += __shfl_xor(p1, m); pc += __shfl_xor(pc, m);
  }
  if (lane == 0) {
    out[49152 + b]       = pc + bco[0];
    out[49408 + 2*b]     = 1.f / (1.f + __expf(-(p0 + bp[0])));
    out[49408 + 2*b + 1] = 1.f / (1.f + __expf(-(p1 + bp[1])));
  }
}

// ---------------------------------------------------------------------------
extern "C" void kernel_launch(void* const* d_in, const int* in_sizes, int n_in,
                              void* d_out, int out_size, void* d_ws, size_t ws_size,
                              hipStream_t stream) {
  const float* inputs = (const float*)d_in[0];
  const float* Wk   = (const float*)d_in[1];
  const float* Wr   = (const float*)d_in[2];
  const float* bias = (const float*)d_in[3];
  const float* Ww   = (const float*)d_in[4];
  const float* bw   = (const float*)d_in[5];
  const float* Wc   = (const float*)d_in[6];
  const float* bc   = (const float*)d_in[7];
  const float* Wcc  = (const float*)d_in[8];
  const float* bcc  = (const float*)d_in[9];
  const float* Wp   = (const float*)d_in[10];
  const float* bp   = (const float*)d_in[11];
  const float* Wco  = (const float*)d_in[12];
  const float* bco  = (const float*)d_in[13];
  float* out = (float*)d_out;
  char* ws = (char*)d_ws;

  // ws layout (bytes):
  // [0x000000) h0 256KB | [0x040000) flags 4KB | [0x041000) h1 256KB
  // [0x081000) warm 256KB | [0x0C1000) cat 8MB (pp0 aliases cat[0:64KB],
  //   pp1 cat[64KB:128KB]; pp used only during lstm, cat built after) |
  // [0x8C1000) partialT 8MB | [0x10C1000) ctT 1MB
  unsigned short* h0   = (unsigned short*)(ws);
  int*            flags= (int*)(ws + 0x40000);
  unsigned short* h1   = (unsigned short*)(ws + 0x41000);
  unsigned short* warm = (unsigned short*)(ws + 0x81000);
  unsigned short* cat  = (unsigned short*)(ws + 0xC1000);
  float*          pp0  = (float*)(ws + 0xC1000);
  float*          pp1  = (float*)(ws + 0xD1000);
  float*          partialT = (float*)(ws + 0x8C1000);
  float*          ctT  = (float*)(ws + 0x10C1000);

  // zero h0 + flags (re-done every launch; ws not re-poisoned between replays)
  hipMemsetAsync(d_ws, 0, 0x41000, stream);

  lstm_kernel<<<TEAMS*MEMBERS, 256, 0, stream>>>(inputs, Wk, Wr, bias, Ww, bw,
                                                 h0, h1, pp0, pp1, warm, flags, out);
  build_cat_kernel<<<4096, 256, 0, stream>>>(inputs, Wc, bc, warm, cat);
  gemm_kernel<<<128, 256, 0, stream>>>(cat, Wcc, partialT);
  reduce_kernel<<<1024, 256, 0, stream>>>(partialT, bcc, ctT);
  head_kernel<<<256, 64, 0, stream>>>(ctT, Wp, bp, Wco, bco, out);

  // inputs passthrough (output 3), offset 49920 floats
  hipMemcpyAsync(out + 49920, inputs, (size_t)65536 * sizeof(float),
                 hipMemcpyDeviceToDevice, stream);
}

// Round 5
// 1087.250 us; speedup vs baseline: 1.0513x; 1.0513x over previous
//
#include <hip/hip_runtime.h>
#include <hip/hip_bf16.h>
#include <stdint.h>

// Problem constants
#define B_    256
#define T_    128
#define W_    32
#define H_    512
#define G4_   2048   // 4*H
#define TW_   96     // warm steps
#define STEPS_ 191   // 96 warm + 95 decode cells
#define TEAMS 8
#define MEMBERS 16
#define ROWS  32     // batch rows per team
#define HC    32     // h-columns per block

typedef __attribute__((ext_vector_type(8))) short short8;
typedef __attribute__((ext_vector_type(4))) float f32x4;
typedef __attribute__((ext_vector_type(4))) uint32_t u32x4;

__device__ __forceinline__ unsigned short f2bf(float f) {
  uint32_t u = __float_as_uint(f);
  u += 0x7fffu + ((u >> 16) & 1u);   // round-to-nearest-even
  return (unsigned short)(u >> 16);
}
__device__ __forceinline__ float sigm(float x) { return 1.f / (1.f + __expf(-x)); }
__device__ __forceinline__ float tanh_(float x) { return 1.f - 2.f / (1.f + __expf(2.f * x)); }

// Coherent (device-scope) ops without cache-maintenance instructions.
#define LOAD_C64(p)     __hip_atomic_load((p), __ATOMIC_RELAXED, __HIP_MEMORY_SCOPE_AGENT)
#define LOAD_CF(p)      __hip_atomic_load((p), __ATOMIC_RELAXED, __HIP_MEMORY_SCOPE_AGENT)
#define LOAD_CI(p)      __hip_atomic_load((p), __ATOMIC_RELAXED, __HIP_MEMORY_SCOPE_AGENT)
#define ARRIVE(p)       __hip_atomic_fetch_add((p), 1, __ATOMIC_RELAXED, __HIP_MEMORY_SCOPE_AGENT)

// Coalesced coherent 16B stores (adjacent lanes -> full-line merges at fabric).
__device__ __forceinline__ void store_cx4(void* p, u32x4 v) {
  asm volatile("global_store_dwordx4 %0, %1, off sc0 sc1" :: "v"(p), "v"(v) : "memory");
}
__device__ __forceinline__ void store_cfx4(void* p, f32x4 v) {
  asm volatile("global_store_dwordx4 %0, %1, off sc0 sc1" :: "v"(p), "v"(v) : "memory");
}

// ---------------------------------------------------------------------------
// Persistent LSTM. 128 blocks x 256 threads. team=blockIdx&7 (rows team*32..),
// member=blockIdx>>3 (h-cols member*32..). Wave w owns 8 h-cols x 4 gates.
// Transposed MFMA: A = Wr^T fragments (VGPR-resident), B = h^T from LDS.
// All 4 gates of one cell land in one lane's f32x4 => in-register cell update.
// Exchange: h + pred-partials via coalesced sc0sc1 dwordx4 stores; barrier =
// per-team monotonic arrive counter (1 atomicAdd per wave after vmcnt drain),
// single poller thread per block.
// ---------------------------------------------------------------------------
__global__ __launch_bounds__(256, 1) void lstm_kernel(
    const float* __restrict__ inputs, const float* __restrict__ Wk,
    const float* __restrict__ Wr, const float* __restrict__ bias,
    const float* __restrict__ Ww, const float* __restrict__ bw,
    unsigned short* __restrict__ h0buf, unsigned short* __restrict__ h1buf,
    float* __restrict__ pp0, float* __restrict__ pp1,
    unsigned short* __restrict__ warm, int* __restrict__ flags,
    float* __restrict__ out_pred)
{
  const int team = blockIdx.x & 7;
  const int member = blockIdx.x >> 3;   // 0..15
  const int rbase = team * ROWS;
  const int hbase = member * HC;
  const int tid = threadIdx.x;
  const int wave = tid >> 6;
  const int lane = tid & 63;
  const int l4 = lane >> 4, l16 = lane & 15;

  __shared__ unsigned short h_lds[ROWS][H_];              // 32KB, XOR swizzled
  __shared__ float x_all_lds[TW_][ROWS][2];               // 24KB warm inputs
  __shared__ float x_lds[ROWS][2];                        // decode x (pred)
  __shared__ float pp_lds[4][ROWS][2];                    // per-wave partials
  __shared__ alignas(16) unsigned short h_out_lds[ROWS][HC];  // 2KB repack

  for (int i = tid; i < TW_*ROWS*2; i += 256) {
    int tt = i >> 6, row = (i >> 1) & 31, c = i & 1;
    x_all_lds[tt][row][c] = inputs[(size_t)(rbase+row)*(T_*2) + (W_+tt)*2 + c];
  }

  // ---- persistent per-lane constants (identical to validated R4) ----
  const int gateL = l16 & 3, hclL = l16 >> 2;
  short8 afrag[2][16];          // Wr^T fragments: 128 VGPRs
  float bbv[2][4], wk0v[2][4], wk1v[2][4], wwv[2][2];
#pragma unroll
  for (int a = 0; a < 2; a++) {
    const int gcA = gateL*H_ + hbase + wave*8 + a*4 + hclL;
#pragma unroll
    for (int ks = 0; ks < 16; ks++) {
      const float* wp = Wr + (size_t)(ks*32 + l4*8) * G4_ + gcA;
#pragma unroll
      for (int j = 0; j < 8; j++) afrag[a][ks][j] = (short)f2bf(wp[(size_t)j * G4_]);
    }
    const int colA = hbase + wave*8 + a*4 + l4;
#pragma unroll
    for (int j = 0; j < 4; j++) {
      int gcj = j*H_ + colA;
      bbv[a][j] = bias[gcj]; wk0v[a][j] = Wk[gcj]; wk1v[a][j] = Wk[G4_ + gcj];
    }
    wwv[a][0] = Ww[2*colA]; wwv[a][1] = Ww[2*colA + 1];
  }
  const float bwc0 = bw[0], bwc1 = bw[1];
  float creg[2][2] = {{0.f,0.f},{0.f,0.f}};
  __syncthreads();

  int* ctr = flags + team * 16;                 // 64B-spaced arrive counter
  const int srow = tid >> 3, sg = tid & 7;      // h-stage decomposition

  for (int t = 0; t < STEPS_; t++) {
    const unsigned short* hprev = (t & 1) ? h1buf : h0buf;
    unsigned short* hnext = (t & 1) ? h0buf : h1buf;
    const float* ppprev = (t & 1) ? pp1 : pp0;
    float* ppnext = (t & 1) ? pp0 : pp1;

    // ---- phase A: decode-x (pp gather) + h slice -> LDS ----
    if (t >= TW_ && tid < 64) {
      int row = tid >> 1, c = tid & 1;
      const float* pps = ppprev + (size_t)team*MEMBERS*64 + row*2 + c;
      float s = c ? bwc1 : bwc0;
#pragma unroll
      for (int m = 0; m < MEMBERS; m++) s += LOAD_CF(pps + m*64);
      x_lds[row][c] = s;
      if (member == 0)
        out_pred[((size_t)(rbase+row)*96 + (t - TW_))*2 + c] = s;
    }
    {
      const uint64_t* src = (const uint64_t*)(hprev + (size_t)(rbase+srow)*H_ + sg*8);
      uint64_t q[16];
#pragma unroll
      for (int i = 0; i < 8; i++) {
        q[2*i]   = LOAD_C64(src + (size_t)i*16);
        q[2*i+1] = LOAD_C64(src + (size_t)i*16 + 1);
      }
#pragma unroll
      for (int i = 0; i < 8; i++) {
        int gr = sg + 8*i;
        uint64_t* d = (uint64_t*)&h_lds[srow][(gr ^ (srow & 7)) * 8];
        d[0] = q[2*i]; d[1] = q[2*i+1];
      }
    }
    __syncthreads();   // S1

    // ---- phase B: z^T = Wr^T @ h^T (+ bias + Wk*x), MFMA over K=512 ----
    f32x4 acc[2][2];
    const float* xsrc = (t < TW_) ? &x_all_lds[t][0][0] : &x_lds[0][0];
#pragma unroll
    for (int a = 0; a < 2; a++)
#pragma unroll
      for (int n = 0; n < 2; n++) {
        int r = n*16 + l16;
        float x0 = xsrc[r*2], x1 = xsrc[r*2+1];
#pragma unroll
        for (int j = 0; j < 4; j++)
          acc[a][n][j] = bbv[a][j] + wk0v[a][j]*x0 + wk1v[a][j]*x1;
      }
#pragma unroll
    for (int ks = 0; ks < 16; ks++) {
      int pg = ((ks*4 + l4) ^ (l16 & 7)) * 8;
      short8 b0 = *(const short8*)&h_lds[l16][pg];
      short8 b1 = *(const short8*)&h_lds[16 + l16][pg];
      acc[0][0] = __builtin_amdgcn_mfma_f32_16x16x32_bf16(afrag[0][ks], b0, acc[0][0], 0,0,0);
      acc[0][1] = __builtin_amdgcn_mfma_f32_16x16x32_bf16(afrag[0][ks], b1, acc[0][1], 0,0,0);
      acc[1][0] = __builtin_amdgcn_mfma_f32_16x16x32_bf16(afrag[1][ks], b0, acc[1][0], 0,0,0);
      acc[1][1] = __builtin_amdgcn_mfma_f32_16x16x32_bf16(afrag[1][ks], b1, acc[1][1], 0,0,0);
    }

    // ---- phase C: in-register cell update -> h_out_lds + pred partials ----
    float pp0v[2] = {0.f, 0.f}, pp1v[2] = {0.f, 0.f};
#pragma unroll
    for (int a = 0; a < 2; a++)
#pragma unroll
      for (int n = 0; n < 2; n++) {
        float zi = acc[a][n][0], zf = acc[a][n][1];
        float zg = acc[a][n][2], zo = acc[a][n][3];
        float cn = sigm(zf)*creg[a][n] + sigm(zi)*tanh_(zg);
        float hn = sigm(zo)*tanh_(cn);
        creg[a][n] = cn;
        pp0v[n] += hn * wwv[a][0];
        pp1v[n] += hn * wwv[a][1];
        h_out_lds[n*16 + l16][wave*8 + a*4 + l4] = f2bf(hn);
      }
    if (t >= TW_ - 1) {
#pragma unroll
      for (int n = 0; n < 2; n++) {
        pp0v[n] += __shfl_xor(pp0v[n], 16); pp0v[n] += __shfl_xor(pp0v[n], 32);
        pp1v[n] += __shfl_xor(pp1v[n], 16); pp1v[n] += __shfl_xor(pp1v[n], 32);
        if (l4 == 0) {
          pp_lds[wave][n*16 + l16][0] = pp0v[n];
          pp_lds[wave][n*16 + l16][1] = pp1v[n];
        }
      }
    }
    __syncthreads();   // S2

    // ---- phase D: coalesced coherent stores ----
    if (tid < 128) {                       // h: 32 rows x 64B, 16B/lane
      int row = tid >> 2, q = tid & 3;
      u32x4 v = *(const u32x4*)&h_out_lds[row][q*8];
      store_cx4(hnext + (size_t)(rbase+row)*H_ + hbase + q*8, v);
      if (t == TW_ - 1)
        *(u32x4*)(warm + (size_t)(rbase+row)*H_ + hbase + q*8) = v;
    }
    if (t >= TW_ - 1 && tid < 16) {        // pp: 256B contiguous per block
      f32x4 pv;
#pragma unroll
      for (int j = 0; j < 4; j++) {
        int row = (tid*4 + j) >> 1, c = (tid*4 + j) & 1;
        pv[j] = pp_lds[0][row][c] + pp_lds[1][row][c]
              + pp_lds[2][row][c] + pp_lds[3][row][c];
      }
      store_cfx4(ppnext + (size_t)(team*MEMBERS + member)*64 + tid*4, pv);
    }

    // ---- barrier: per-wave drain + arrive; single poller; one sync ----
    asm volatile("s_waitcnt vmcnt(0)" ::: "memory");
    if (lane == 0) ARRIVE(ctr);
    if (tid == 0) {
      int need = 64 * (t + 1);             // 16 members x 4 waves
      while (LOAD_CI(ctr) < need) {}
    }
    __syncthreads();   // S4
  }

  // ---- final pred (k=95) from pp of step 190 (pp1 side) ----
  if (member == 0 && tid < 64) {
    int row = tid >> 1, c = tid & 1;
    const float* pps = pp1 + (size_t)team*MEMBERS*64 + row*2 + c;
    float s = c ? bwc1 : bwc0;
#pragma unroll
    for (int m = 0; m < MEMBERS; m++) s += LOAD_CF(pps + m*64);
    out_pred[((size_t)(rbase+row)*96 + 95)*2 + c] = s;
  }
}

// ---------------------------------------------------------------------------
// cat = [warm_out (bf16) | relu(inputs[:, :31] @ Wc + bc)] as bf16 [256][16384]
// ---------------------------------------------------------------------------
__global__ void build_cat_kernel(
    const float* __restrict__ inputs, const float* __restrict__ Wc,
    const float* __restrict__ bc, const unsigned short* __restrict__ warm,
    unsigned short* __restrict__ cat)
{
  int idx = (blockIdx.x * 256 + threadIdx.x) * 4;   // 4096 blocks
  int b = idx >> 14, k0 = idx & 16383;
  uint2 out;
  if (k0 < 512) {
    out = *(const uint2*)(warm + (size_t)b*512 + k0);
  } else {
    int kk = k0 - 512;
    int w = kk >> 9;
    int hc = kk & 511;
    float x0 = inputs[(size_t)b*256 + w*2], x1 = inputs[(size_t)b*256 + w*2 + 1];
    unsigned short v[4];
#pragma unroll
    for (int j = 0; j < 4; j++) {
      float val = x0 * Wc[hc+j] + x1 * Wc[512 + hc + j] + bc[hc+j];
      v[j] = f2bf(fmaxf(val, 0.f));
    }
    out.x = (uint32_t)v[0] | ((uint32_t)v[1] << 16);
    out.y = (uint32_t)v[2] | ((uint32_t)v[3] << 16);
  }
  *(uint2*)(cat + idx) = out;
}

// ---------------------------------------------------------------------------
// Transposed GEMM: partialT[kc][n][b] = sum_k Wcc[k][n]*cat[b][k] over k-chunk.
// ---------------------------------------------------------------------------
__global__ __launch_bounds__(256, 1) void gemm_kernel(
    const unsigned short* __restrict__ cat, const float* __restrict__ Wcc,
    float* __restrict__ partialT)
{
  const int nc = blockIdx.x & 15;
  const int kc = blockIdx.x >> 4;
  const int tid = threadIdx.x;
  const int w = tid >> 6, lane = tid & 63;
  const int l4 = lane >> 4, l16 = lane & 15;

  f32x4 zero = {0.f, 0.f, 0.f, 0.f};
  f32x4 acc[16];
#pragma unroll
  for (int i = 0; i < 16; i++) acc[i] = zero;

  const int kbase = kc * 2048;
  const int nrow = nc*64 + w*16 + l16;

  for (int ks = 0; ks < 64; ks++) {
    const float* wp = Wcc + (size_t)(kbase + ks*32 + l4*8) * 1024 + nrow;
    short8 af;
#pragma unroll
    for (int j = 0; j < 8; j++) af[j] = (short)f2bf(wp[(size_t)j * 1024]);
    const unsigned short* cp = cat + kbase + ks*32 + l4*8;
#pragma unroll
    for (int bt = 0; bt < 16; bt++) {
      short8 bf = *(const short8*)(cp + (size_t)(bt*16 + l16) * 16384);
      acc[bt] = __builtin_amdgcn_mfma_f32_16x16x32_bf16(af, bf, acc[bt], 0, 0, 0);
    }
  }

  float* pp = partialT + (size_t)kc*1024*256 + (size_t)(nc*64 + w*16 + l4*4)*256 + l16;
#pragma unroll
  for (int bt = 0; bt < 16; bt++) {
#pragma unroll
    for (int r = 0; r < 4; r++)
      pp[(size_t)r*256 + bt*16] = acc[bt][r];
  }
}

// ctT[n][b] = relu(bcc[n] + sum_p partialT[p][n][b])
__global__ void reduce_kernel(const float* __restrict__ partialT,
                              const float* __restrict__ bcc, float* __restrict__ ctT)
{
  int e = blockIdx.x * 256 + threadIdx.x;   // 1024 blocks
  int n = e >> 8;
  float s = bcc[n];
#pragma unroll
  for (int p = 0; p < 8; p++) s += partialT[(size_t)p*262144 + e];
  ctT[e] = fmaxf(s, 0.f);
}

// cost/prob heads: one wave per batch row
__global__ void head_kernel(const float* __restrict__ ctT, const float* __restrict__ Wp,
                            const float* __restrict__ bp, const float* __restrict__ Wco,
                            const float* __restrict__ bco, float* __restrict__ out)
{
  int b = blockIdx.x;
  int lane = threadIdx.x;
  float p0 = 0.f, p1 = 0.f, pc = 0.f;
#pragma unroll
  for (int i = 0; i < 16; i++) {
    int n = i*64 + lane;
    float c = ctT[(size_t)n*256 + b];
    p0 += c * Wp[2*n]; p1 += c * Wp[2*n+1]; pc += c * Wco[n];
  }
  for (int m = 1; m < 64; m <<= 1) {
    p0 += __shfl_xor(p0, m); p1 += __shfl_xor(p1, m); pc += __shfl_xor(pc, m);
  }
  if (lane == 0) {
    out[49152 + b]       = pc + bco[0];
    out[49408 + 2*b]     = 1.f / (1.f + __expf(-(p0 + bp[0])));
    out[49408 + 2*b + 1] = 1.f / (1.f + __expf(-(p1 + bp[1])));
  }
}

// ---------------------------------------------------------------------------
extern "C" void kernel_launch(void* const* d_in, const int* in_sizes, int n_in,
                              void* d_out, int out_size, void* d_ws, size_t ws_size,
                              hipStream_t stream) {
  const float* inputs = (const float*)d_in[0];
  const float* Wk   = (const float*)d_in[1];
  const float* Wr   = (const float*)d_in[2];
  const float* bias = (const float*)d_in[3];
  const float* Ww   = (const float*)d_in[4];
  const float* bw   = (const float*)d_in[5];
  const float* Wc   = (const float*)d_in[6];
  const float* bc   = (const float*)d_in[7];
  const float* Wcc  = (const float*)d_in[8];
  const float* bcc  = (const float*)d_in[9];
  const float* Wp   = (const float*)d_in[10];
  const float* bp   = (const float*)d_in[11];
  const float* Wco  = (const float*)d_in[12];
  const float* bco  = (const float*)d_in[13];
  float* out = (float*)d_out;
  char* ws = (char*)d_ws;

  // ws layout (bytes):
  // [0x000000) h0 256KB | [0x040000) flags/counters 4KB | [0x041000) h1 256KB
  // [0x081000) warm 256KB | [0x0C1000) cat 8MB (pp0 aliases cat[0:32KB],
  //   pp1 cat[32KB:64KB]; pp used only during lstm, cat built after) |
  // [0x8C1000) partialT 8MB | [0x10C1000) ctT 1MB
  unsigned short* h0   = (unsigned short*)(ws);
  int*            flags= (int*)(ws + 0x40000);
  unsigned short* h1   = (unsigned short*)(ws + 0x41000);
  unsigned short* warm = (unsigned short*)(ws + 0x81000);
  unsigned short* cat  = (unsigned short*)(ws + 0xC1000);
  float*          pp0  = (float*)(ws + 0xC1000);
  float*          pp1  = (float*)(ws + 0xC9000);
  float*          partialT = (float*)(ws + 0x8C1000);
  float*          ctT  = (float*)(ws + 0x10C1000);

  // zero h0 + counters (re-done every launch; ws not re-poisoned between replays)
  hipMemsetAsync(d_ws, 0, 0x41000, stream);

  lstm_kernel<<<TEAMS*MEMBERS, 256, 0, stream>>>(inputs, Wk, Wr, bias, Ww, bw,
                                                 h0, h1, pp0, pp1, warm, flags, out);
  build_cat_kernel<<<4096, 256, 0, stream>>>(inputs, Wc, bc, warm, cat);
  gemm_kernel<<<128, 256, 0, stream>>>(cat, Wcc, partialT);
  reduce_kernel<<<1024, 256, 0, stream>>>(partialT, bcc, ctT);
  head_kernel<<<256, 64, 0, stream>>>(ctT, Wp, bp, Wco, bco, out);

  // inputs passthrough (output 3), offset 49920 floats
  hipMemcpyAsync(out + 49920, inputs, (size_t)65536 * sizeof(float),
                 hipMemcpyDeviceToDevice, stream);
}

// Round 6
// 779.959 us; speedup vs baseline: 1.4654x; 1.3940x over previous
//
#include <hip/hip_runtime.h>
#include <hip/hip_bf16.h>
#include <stdint.h>

// Problem constants
#define B_    256
#define T_    128
#define W_    32
#define H_    512
#define G4_   2048   // 4*H
#define TW_   96     // warm steps
#define STEPS_ 191   // 96 warm + 95 decode cells
#define TEAMS 16
#define MEMBERS 16
#define ROWS  16     // batch rows per team
#define HC    32     // h-columns per block

typedef __attribute__((ext_vector_type(8))) short short8;
typedef __attribute__((ext_vector_type(4))) float f32x4;
typedef __attribute__((ext_vector_type(4))) uint32_t u32x4;

__device__ __forceinline__ unsigned short f2bf(float f) {
  uint32_t u = __float_as_uint(f);
  u += 0x7fffu + ((u >> 16) & 1u);   // round-to-nearest-even
  return (unsigned short)(u >> 16);
}
__device__ __forceinline__ float sigm(float x) { return 1.f / (1.f + __expf(-x)); }
__device__ __forceinline__ float tanh_(float x) { return 1.f - 2.f / (1.f + __expf(2.f * x)); }

// Coherent (device-scope) ops without cache-maintenance instructions.
#define LOAD_CF(p)      __hip_atomic_load((p), __ATOMIC_RELAXED, __HIP_MEMORY_SCOPE_AGENT)
#define LOAD_CI(p)      __hip_atomic_load((p), __ATOMIC_RELAXED, __HIP_MEMORY_SCOPE_AGENT)
#define ARRIVE(p)       __hip_atomic_fetch_add((p), 1, __ATOMIC_RELAXED, __HIP_MEMORY_SCOPE_AGENT)

// Coalesced coherent 16B ops (LLC point of coherence, no wbl2/inv).
__device__ __forceinline__ u32x4 load_cx4(const void* p) {
  u32x4 v;
  asm volatile("global_load_dwordx4 %0, %1, off sc0 sc1"
               : "=v"(v) : "v"(p) : "memory");
  return v;   // caller must s_waitcnt vmcnt before use
}
__device__ __forceinline__ void store_cx4(void* p, u32x4 v) {
  asm volatile("global_store_dwordx4 %0, %1, off sc0 sc1" :: "v"(p), "v"(v) : "memory");
}
__device__ __forceinline__ void store_cfx4(void* p, f32x4 v) {
  asm volatile("global_store_dwordx4 %0, %1, off sc0 sc1" :: "v"(p), "v"(v) : "memory");
}

// ---------------------------------------------------------------------------
// Persistent LSTM. 256 blocks x 256 threads (1 block/CU, all co-resident).
// team = blockIdx&15 (rows team*16..+16), member = blockIdx>>4 (cols member*32)
// Wave w owns 8 h-cols x 4 gates. Transposed MFMA: A = Wr^T frags (VGPRs),
// B = h^T from LDS. All 4 gates of one cell in one lane => in-register cell.
// Exchange: coalesced sc0sc1 dwordx4; barrier = one atomicAdd per block into
// a per-team monotonic counter after per-wave vmcnt drain + block sync.
// ---------------------------------------------------------------------------
__global__ __launch_bounds__(256, 1) void lstm_kernel(
    const float* __restrict__ inputs, const float* __restrict__ Wk,
    const float* __restrict__ Wr, const float* __restrict__ bias,
    const float* __restrict__ Ww, const float* __restrict__ bw,
    unsigned short* __restrict__ h0buf, unsigned short* __restrict__ h1buf,
    float* __restrict__ pp0, float* __restrict__ pp1,
    unsigned short* __restrict__ warm, int* __restrict__ flags,
    float* __restrict__ out_pred)
{
  const int team = blockIdx.x & 15;
  const int member = blockIdx.x >> 4;   // 0..15
  const int rbase = team * ROWS;
  const int hbase = member * HC;
  const int tid = threadIdx.x;
  const int wave = tid >> 6;
  const int lane = tid & 63;
  const int l4 = lane >> 4, l16 = lane & 15;

  __shared__ unsigned short h_lds[ROWS][H_];              // 16KB, XOR swizzled
  __shared__ float x_all_lds[TW_][ROWS][2];               // 12KB warm inputs
  __shared__ float x_lds[ROWS][2];                        // decode x (pred)
  __shared__ float pp_lds[4][ROWS][2];                    // per-wave partials
  __shared__ alignas(16) unsigned short h_out_lds[ROWS][HC];  // 1KB repack

  for (int i = tid; i < TW_*ROWS*2; i += 256) {
    int tt = i >> 5, row = (i >> 1) & 15, c = i & 1;
    x_all_lds[tt][row][c] = inputs[(size_t)(rbase+row)*(T_*2) + (W_+tt)*2 + c];
  }

  // ---- persistent per-lane constants (same math as validated R4/R5) ----
  const int gateL = l16 & 3, hclL = l16 >> 2;
  short8 afrag[2][16];          // Wr^T fragments: 128 VGPRs
  float bbv[2][4], wk0v[2][4], wk1v[2][4], wwv[2][2];
#pragma unroll
  for (int a = 0; a < 2; a++) {
    const int gcA = gateL*H_ + hbase + wave*8 + a*4 + hclL;
#pragma unroll
    for (int ks = 0; ks < 16; ks++) {
      const float* wp = Wr + (size_t)(ks*32 + l4*8) * G4_ + gcA;
#pragma unroll
      for (int j = 0; j < 8; j++) afrag[a][ks][j] = (short)f2bf(wp[(size_t)j * G4_]);
    }
    const int colA = hbase + wave*8 + a*4 + l4;
#pragma unroll
    for (int j = 0; j < 4; j++) {
      int gcj = j*H_ + colA;
      bbv[a][j] = bias[gcj]; wk0v[a][j] = Wk[gcj]; wk1v[a][j] = Wk[G4_ + gcj];
    }
    wwv[a][0] = Ww[2*colA]; wwv[a][1] = Ww[2*colA + 1];
  }
  const float bwc0 = bw[0], bwc1 = bw[1];
  float creg[2] = {0.f, 0.f};
  __syncthreads();

  int* ctr = flags + team * 16;                 // 64B-spaced arrive counter
  const int srow = tid >> 4, sg = tid & 15;     // h-stage: 16 thr/row, 16B granules

  for (int t = 0; t < STEPS_; t++) {
    const unsigned short* hprev = (t & 1) ? h1buf : h0buf;
    unsigned short* hnext = (t & 1) ? h0buf : h1buf;
    const float* ppprev = (t & 1) ? pp1 : pp0;
    float* ppnext = (t & 1) ? pp0 : pp1;

    // ---- phase A: decode-x (pp gather) + h slice -> LDS ----
    if (t >= TW_ && tid < 32) {
      int row = tid >> 1, c = tid & 1;
      const float* pps = ppprev + (size_t)team*MEMBERS*32 + row*2 + c;
      float s = c ? bwc1 : bwc0;
#pragma unroll
      for (int m = 0; m < MEMBERS; m++) s += LOAD_CF(pps + m*32);
      x_lds[row][c] = s;
      if (member == 0)
        out_pred[((size_t)(rbase+row)*96 + (t - TW_))*2 + c] = s;
    }
    {
      const unsigned short* srcb = hprev + (size_t)(rbase+srow)*H_ + sg*8;
      u32x4 q[4];
#pragma unroll
      for (int i = 0; i < 4; i++) q[i] = load_cx4(srcb + i*128);   // granule sg+16i
      asm volatile("s_waitcnt vmcnt(0)" ::: "memory");
      __builtin_amdgcn_sched_barrier(0);
#pragma unroll
      for (int i = 0; i < 4; i++)
        *(u32x4*)&h_lds[srow][((sg + 16*i) ^ (srow & 7)) * 8] = q[i];
    }
    __syncthreads();   // S1

    // ---- phase B: z^T = Wr^T @ h^T (+ bias + Wk*x), MFMA over K=512 ----
    f32x4 acc[2];
    const float* xsrc = (t < TW_) ? &x_all_lds[t][0][0] : &x_lds[0][0];
    {
      float x0 = xsrc[2*l16], x1 = xsrc[2*l16 + 1];
#pragma unroll
      for (int a = 0; a < 2; a++)
#pragma unroll
        for (int j = 0; j < 4; j++)
          acc[a][j] = bbv[a][j] + wk0v[a][j]*x0 + wk1v[a][j]*x1;
    }
#pragma unroll
    for (int ks = 0; ks < 16; ks++) {
      int pg = ((ks*4 + l4) ^ (l16 & 7)) * 8;
      short8 b0 = *(const short8*)&h_lds[l16][pg];
      acc[0] = __builtin_amdgcn_mfma_f32_16x16x32_bf16(afrag[0][ks], b0, acc[0], 0,0,0);
      acc[1] = __builtin_amdgcn_mfma_f32_16x16x32_bf16(afrag[1][ks], b0, acc[1], 0,0,0);
    }

    // ---- phase C: in-register cell update -> h_out_lds + pred partials ----
    float pp0v = 0.f, pp1v = 0.f;
#pragma unroll
    for (int a = 0; a < 2; a++) {
      float zi = acc[a][0], zf = acc[a][1], zg = acc[a][2], zo = acc[a][3];
      float cn = sigm(zf)*creg[a] + sigm(zi)*tanh_(zg);
      float hn = sigm(zo)*tanh_(cn);
      creg[a] = cn;
      pp0v += hn * wwv[a][0];
      pp1v += hn * wwv[a][1];
      h_out_lds[l16][wave*8 + a*4 + l4] = f2bf(hn);
    }
    if (t >= TW_ - 1) {
      pp0v += __shfl_xor(pp0v, 16); pp0v += __shfl_xor(pp0v, 32);
      pp1v += __shfl_xor(pp1v, 16); pp1v += __shfl_xor(pp1v, 32);
      if (l4 == 0) {
        pp_lds[wave][l16][0] = pp0v;
        pp_lds[wave][l16][1] = pp1v;
      }
    }
    __syncthreads();   // S2

    // ---- phase D: coalesced coherent stores ----
    if (tid < 64) {                        // h: 16 rows x 64B, 16B/lane
      int row = tid >> 2, q = tid & 3;
      u32x4 v = *(const u32x4*)&h_out_lds[row][q*8];
      store_cx4(hnext + (size_t)(rbase+row)*H_ + hbase + q*8, v);
      if (t == TW_ - 1)
        *(u32x4*)(warm + (size_t)(rbase+row)*H_ + hbase + q*8) = v;
    }
    if (t >= TW_ - 1 && tid < 8) {         // pp: 128B contiguous per block
      f32x4 pv;
#pragma unroll
      for (int j = 0; j < 4; j++) {
        int idx = tid*4 + j, row = idx >> 1, c = idx & 1;
        pv[j] = pp_lds[0][row][c] + pp_lds[1][row][c]
              + pp_lds[2][row][c] + pp_lds[3][row][c];
      }
      store_cfx4(ppnext + (size_t)(team*MEMBERS + member)*32 + tid*4, pv);
    }

    // ---- barrier: drain all waves, ONE arrive per block, poll, release ----
    asm volatile("s_waitcnt vmcnt(0)" ::: "memory");
    __syncthreads();   // S3: every wave's stores at coherence point
    if (tid == 0) {
      ARRIVE(ctr);
      int need = MEMBERS * (t + 1);
      while (LOAD_CI(ctr) < need) {}
    }
    __syncthreads();   // S4
  }

  // ---- final pred (k=95) from pp of step 190 (pp1 side) ----
  if (member == 0 && tid < 32) {
    int row = tid >> 1, c = tid & 1;
    const float* pps = pp1 + (size_t)team*MEMBERS*32 + row*2 + c;
    float s = c ? bwc1 : bwc0;
#pragma unroll
    for (int m = 0; m < MEMBERS; m++) s += LOAD_CF(pps + m*32);
    out_pred[((size_t)(rbase+row)*96 + 95)*2 + c] = s;
  }
}

// ---------------------------------------------------------------------------
// cat = [warm_out (bf16) | relu(inputs[:, :31] @ Wc + bc)] as bf16 [256][16384]
// ---------------------------------------------------------------------------
__global__ void build_cat_kernel(
    const float* __restrict__ inputs, const float* __restrict__ Wc,
    const float* __restrict__ bc, const unsigned short* __restrict__ warm,
    unsigned short* __restrict__ cat)
{
  int idx = (blockIdx.x * 256 + threadIdx.x) * 4;   // 4096 blocks
  int b = idx >> 14, k0 = idx & 16383;
  uint2 out;
  if (k0 < 512) {
    out = *(const uint2*)(warm + (size_t)b*512 + k0);
  } else {
    int kk = k0 - 512;
    int w = kk >> 9;
    int hc = kk & 511;
    float x0 = inputs[(size_t)b*256 + w*2], x1 = inputs[(size_t)b*256 + w*2 + 1];
    unsigned short v[4];
#pragma unroll
    for (int j = 0; j < 4; j++) {
      float val = x0 * Wc[hc+j] + x1 * Wc[512 + hc + j] + bc[hc+j];
      v[j] = f2bf(fmaxf(val, 0.f));
    }
    out.x = (uint32_t)v[0] | ((uint32_t)v[1] << 16);
    out.y = (uint32_t)v[2] | ((uint32_t)v[3] << 16);
  }
  *(uint2*)(cat + idx) = out;
}

// ---------------------------------------------------------------------------
// Transposed GEMM: partialT[kc][n][b] = sum_k Wcc[k][n]*cat[b][k] over k-chunk.
// ---------------------------------------------------------------------------
__global__ __launch_bounds__(256, 1) void gemm_kernel(
    const unsigned short* __restrict__ cat, const float* __restrict__ Wcc,
    float* __restrict__ partialT)
{
  const int nc = blockIdx.x & 15;
  const int kc = blockIdx.x >> 4;
  const int tid = threadIdx.x;
  const int w = tid >> 6, lane = tid & 63;
  const int l4 = lane >> 4, l16 = lane & 15;

  f32x4 zero = {0.f, 0.f, 0.f, 0.f};
  f32x4 acc[16];
#pragma unroll
  for (int i = 0; i < 16; i++) acc[i] = zero;

  const int kbase = kc * 2048;
  const int nrow = nc*64 + w*16 + l16;

  for (int ks = 0; ks < 64; ks++) {
    const float* wp = Wcc + (size_t)(kbase + ks*32 + l4*8) * 1024 + nrow;
    short8 af;
#pragma unroll
    for (int j = 0; j < 8; j++) af[j] = (short)f2bf(wp[(size_t)j * 1024]);
    const unsigned short* cp = cat + kbase + ks*32 + l4*8;
#pragma unroll
    for (int bt = 0; bt < 16; bt++) {
      short8 bf = *(const short8*)(cp + (size_t)(bt*16 + l16) * 16384);
      acc[bt] = __builtin_amdgcn_mfma_f32_16x16x32_bf16(af, bf, acc[bt], 0, 0, 0);
    }
  }

  float* pp = partialT + (size_t)kc*1024*256 + (size_t)(nc*64 + w*16 + l4*4)*256 + l16;
#pragma unroll
  for (int bt = 0; bt < 16; bt++) {
#pragma unroll
    for (int r = 0; r < 4; r++)
      pp[(size_t)r*256 + bt*16] = acc[bt][r];
  }
}

// ctT[n][b] = relu(bcc[n] + sum_p partialT[p][n][b])
__global__ void reduce_kernel(const float* __restrict__ partialT,
                              const float* __restrict__ bcc, float* __restrict__ ctT)
{
  int e = blockIdx.x * 256 + threadIdx.x;   // 1024 blocks
  int n = e >> 8;
  float s = bcc[n];
#pragma unroll
  for (int p = 0; p < 8; p++) s += partialT[(size_t)p*262144 + e];
  ctT[e] = fmaxf(s, 0.f);
}

// cost/prob heads: one wave per batch row
__global__ void head_kernel(const float* __restrict__ ctT, const float* __restrict__ Wp,
                            const float* __restrict__ bp, const float* __restrict__ Wco,
                            const float* __restrict__ bco, float* __restrict__ out)
{
  int b = blockIdx.x;
  int lane = threadIdx.x;
  float p0 = 0.f, p1 = 0.f, pc = 0.f;
#pragma unroll
  for (int i = 0; i < 16; i++) {
    int n = i*64 + lane;
    float c = ctT[(size_t)n*256 + b];
    p0 += c * Wp[2*n]; p1 += c * Wp[2*n+1]; pc += c * Wco[n];
  }
  for (int m = 1; m < 64; m <<= 1) {
    p0 += __shfl_xor(p0, m); p1 += __shfl_xor(p1, m); pc += __shfl_xor(pc, m);
  }
  if (lane == 0) {
    out[49152 + b]       = pc + bco[0];
    out[49408 + 2*b]     = 1.f / (1.f + __expf(-(p0 + bp[0])));
    out[49408 + 2*b + 1] = 1.f / (1.f + __expf(-(p1 + bp[1])));
  }
}

// ---------------------------------------------------------------------------
extern "C" void kernel_launch(void* const* d_in, const int* in_sizes, int n_in,
                              void* d_out, int out_size, void* d_ws, size_t ws_size,
                              hipStream_t stream) {
  const float* inputs = (const float*)d_in[0];
  const float* Wk   = (const float*)d_in[1];
  const float* Wr   = (const float*)d_in[2];
  const float* bias = (const float*)d_in[3];
  const float* Ww   = (const float*)d_in[4];
  const float* bw   = (const float*)d_in[5];
  const float* Wc   = (const float*)d_in[6];
  const float* bc   = (const float*)d_in[7];
  const float* Wcc  = (const float*)d_in[8];
  const float* bcc  = (const float*)d_in[9];
  const float* Wp   = (const float*)d_in[10];
  const float* bp   = (const float*)d_in[11];
  const float* Wco  = (const float*)d_in[12];
  const float* bco  = (const float*)d_in[13];
  float* out = (float*)d_out;
  char* ws = (char*)d_ws;

  // ws layout (bytes):
  // [0x000000) h0 256KB | [0x040000) flags/counters 4KB | [0x041000) h1 256KB
  // [0x081000) warm 256KB | [0x0C1000) cat 8MB (pp0 aliases cat[0:32KB],
  //   pp1 cat[32KB:64KB]; pp used only during lstm, cat built after) |
  // [0x8C1000) partialT 8MB | [0x10C1000) ctT 1MB
  unsigned short* h0   = (unsigned short*)(ws);
  int*            flags= (int*)(ws + 0x40000);
  unsigned short* h1   = (unsigned short*)(ws + 0x41000);
  unsigned short* warm = (unsigned short*)(ws + 0x81000);
  unsigned short* cat  = (unsigned short*)(ws + 0xC1000);
  float*          pp0  = (float*)(ws + 0xC1000);
  float*          pp1  = (float*)(ws + 0xC9000);
  float*          partialT = (float*)(ws + 0x8C1000);
  float*          ctT  = (float*)(ws + 0x10C1000);

  // zero h0 + counters (re-done every launch; ws not re-poisoned between replays)
  hipMemsetAsync(d_ws, 0, 0x41000, stream);

  lstm_kernel<<<TEAMS*MEMBERS, 256, 0, stream>>>(inputs, Wk, Wr, bias, Ww, bw,
                                                 h0, h1, pp0, pp1, warm, flags, out);
  build_cat_kernel<<<4096, 256, 0, stream>>>(inputs, Wc, bc, warm, cat);
  gemm_kernel<<<128, 256, 0, stream>>>(cat, Wcc, partialT);
  reduce_kernel<<<1024, 256, 0, stream>>>(partialT, bcc, ctT);
  head_kernel<<<256, 64, 0, stream>>>(ctT, Wp, bp, Wco, bco, out);

  // inputs passthrough (output 3), offset 49920 floats
  hipMemcpyAsync(out + 49920, inputs, (size_t)65536 * sizeof(float),
                 hipMemcpyDeviceToDevice, stream);
}